// Round 4
// baseline (3774.005 us; speedup 1.0000x reference)
//
#include <hip/hip_runtime.h>
#include <hip/hip_bf16.h>

#define NPTS    200000
#define MPIL    30000
#define BATCH   2
#define GRID0   256
#define PCMIN   (-51.2f)
#define VOXEL0  (0.4f)

#define SLOT_B  ((size_t)16777216)   // bf16 activation slot: 2*256*256*64*2
#define SLOT_F  ((size_t)33554432)   // fp32 activation slot

// weight pool offsets (in floats), pool lives at d_out + 3*slot
#define W0F 0
#define W1F 256
#define K1D 2304
#define K11 39168
#define K12 76032
#define K2D 112896
#define K21 186624
#define K22 334080

// ws layout (bytes)
#define WS_FLAG 0
#define WS_OCC8 64
#define WS_OCC1 (64 + 131072)
#define WS_OCC2 (64 + 262144)
#define WS_HMAX 393280            // [M,16] f32 (dead after pfn1)
#define WS_FV   2313280           // [M,64] f32 (dead after scatter)
#define WS_FX   393344            // final x, up to 16MB (written at conv6; overlaps hmax/fv lifetimes-disjoint)

static __device__ __forceinline__ float b2f(__hip_bfloat16 v) { return __bfloat162float(v); }
static __device__ __forceinline__ unsigned short f2bbits(float f) {
    __hip_bfloat16 h = __float2bfloat16(f);
    union { __hip_bfloat16 h; unsigned short u; } cv; cv.h = h; return cv.u;
}
static __device__ __forceinline__ float lo2f(unsigned int u) {
    union { unsigned int u; float f; } c; c.u = u << 16; return c.f;
}
static __device__ __forceinline__ float hi2f(unsigned int u) {
    union { unsigned int u; float f; } c; c.u = u & 0xFFFF0000u; return c.f;
}
static __device__ __forceinline__ unsigned int pack2(float a, float b) {
    return (unsigned int)f2bbits(a) | ((unsigned int)f2bbits(b) << 16);
}

// dtype-adaptive accessors (isb=1: bf16, isb=0: fp32); index in elements
static __device__ __forceinline__ float ldf(const void* p, size_t i, int isb) {
    return isb ? b2f(((const __hip_bfloat16*)p)[i]) : ((const float*)p)[i];
}
static __device__ __forceinline__ float4 ld4(const void* p, size_t i, int isb) {
    if (isb) {
        uint2 r = *(const uint2*)((const __hip_bfloat16*)p + i);
        return make_float4(lo2f(r.x), hi2f(r.x), lo2f(r.y), hi2f(r.y));
    }
    return *(const float4*)((const float*)p + i);
}
static __device__ __forceinline__ void st4(void* p, size_t i, int isb, float4 v) {
    if (isb) {
        uint2 pk; pk.x = pack2(v.x, v.y); pk.y = pack2(v.z, v.w);
        *(uint2*)((__hip_bfloat16*)p + i) = pk;
    } else {
        *(float4*)((float*)p + i) = v;
    }
}
static __device__ __forceinline__ void* actptr(void* ob, int slot, int isb) {
    return (char*)ob + (size_t)slot * (isb ? SLOT_B : SLOT_F);
}
static __device__ __forceinline__ float* wpool(void* ob, int isb) {
    return (float*)((char*)ob + 3 * (isb ? SLOT_B : SLOT_F));
}

// ---------------- dtype probe ----------------
__global__ void probe_kernel(const unsigned short* __restrict__ g0, int* __restrict__ flag) {
    if (threadIdx.x == 0 && blockIdx.x == 0) {
        int ok = 1;
        for (int i = 0; i < 8; i++) {
            unsigned short u = g0[i];
            if (u < 0x3E00 || u >= 0x4000) ok = 0;   // bf16 of [0.5,1.0] lands in [0x3F00,0x3F80]
        }
        *flag = ok;
    }
}

// ---------------- weight conversion -> fp32 pool ----------------
__global__ __launch_bounds__(256) void cvt_kernel(const void* __restrict__ src, void* ob,
                                                  int woff, int n, const int* __restrict__ flag) {
    int isb = *flag;
    int i = blockIdx.x * 256 + threadIdx.x;
    if (i < n) wpool(ob, isb)[woff + i] = ldf(src, i, isb);
}

// ---------------- PFN layer 0 ----------------
__global__ __launch_bounds__(256) void pfn0_kernel(
    const void* __restrict__ feat, void* ob, const void* __restrict__ g0,
    const void* __restrict__ b0, const int* __restrict__ unq_inv,
    float* __restrict__ hmax, const int* __restrict__ flag)
{
    const int isb = *flag;
    int n = blockIdx.x * 256 + threadIdx.x;
    if (n >= NPTS) return;
    const float* w0f = wpool(ob, isb) + W0F;
    void* h0 = actptr(ob, 1, isb);
    float f[16];
#pragma unroll
    for (int i = 0; i < 16; i += 4) {
        float4 v = ld4(feat, (size_t)n * 16 + i, isb);
        f[i] = v.x; f[i + 1] = v.y; f[i + 2] = v.z; f[i + 3] = v.w;
    }
    int p = unq_inv[n];
#pragma unroll
    for (int co = 0; co < 16; co += 4) {
        float a0 = 0.f, a1 = 0.f, a2 = 0.f, a3 = 0.f;
#pragma unroll
        for (int ci = 0; ci < 16; ci++) {
            float4 w = *(const float4*)&w0f[ci * 16 + co];
            a0 += f[ci] * w.x; a1 += f[ci] * w.y; a2 += f[ci] * w.z; a3 += f[ci] * w.w;
        }
        float o[4] = { a0, a1, a2, a3 };
#pragma unroll
        for (int k = 0; k < 4; k++) {
            float z = o[k] * ldf(g0, co + k, isb) + ldf(b0, co + k, isb);
            o[k] = fmaxf(z, 0.f);
            atomicMax((unsigned int*)(hmax + (size_t)p * 16 + co + k), __float_as_uint(o[k]));
        }
        st4(h0, (size_t)n * 16 + co, isb, make_float4(o[0], o[1], o[2], o[3]));
    }
}

// ---------------- PFN layer 1 ----------------
__global__ __launch_bounds__(256) void pfn1_kernel(
    void* ob, const float* __restrict__ hmax, const void* __restrict__ g1,
    const void* __restrict__ b1, const int* __restrict__ unq_inv,
    float* __restrict__ fv, const int* __restrict__ flag)
{
    const int isb = *flag;
    int n = blockIdx.x * 256 + threadIdx.x;
    if (n >= NPTS) return;
    const float* w1f = wpool(ob, isb) + W1F;
    const void* h0 = actptr(ob, 1, isb);
    int p = unq_inv[n];
    float hin[32];
#pragma unroll
    for (int i = 0; i < 16; i += 4) {
        float4 a = ld4(h0, (size_t)n * 16 + i, isb);
        hin[i] = a.x; hin[i + 1] = a.y; hin[i + 2] = a.z; hin[i + 3] = a.w;
        float4 b = *(const float4*)&hmax[(size_t)p * 16 + i];
        hin[16 + i] = b.x; hin[17 + i] = b.y; hin[18 + i] = b.z; hin[19 + i] = b.w;
    }
    for (int co = 0; co < 64; co += 4) {
        float a0 = 0.f, a1 = 0.f, a2 = 0.f, a3 = 0.f;
#pragma unroll
        for (int ci = 0; ci < 32; ci++) {
            float4 w = *(const float4*)&w1f[ci * 64 + co];
            a0 += hin[ci] * w.x; a1 += hin[ci] * w.y; a2 += hin[ci] * w.z; a3 += hin[ci] * w.w;
        }
        float zz[4] = { a0, a1, a2, a3 };
#pragma unroll
        for (int k = 0; k < 4; k++) {
            float z = zz[k] * ldf(g1, co + k, isb) + ldf(b1, co + k, isb);
            z = fmaxf(z, 0.f);
            atomicMax((unsigned int*)(fv + (size_t)p * 64 + co + k), __float_as_uint(z));
        }
    }
}

// ---------------- scatter fv -> dense BEV + occupancy ----------------
__global__ __launch_bounds__(256) void scatter_kernel(
    const float* __restrict__ fv, const int* __restrict__ unq,
    void* ob, unsigned char* __restrict__ occ, const int* __restrict__ flag)
{
    const int isb = *flag;
    int idx = blockIdx.x * 256 + threadIdx.x;
    if (idx >= MPIL * 16) return;
    void* img = actptr(ob, 0, isb);
    int m = idx >> 4, cg = idx & 15;
    int b = unq[m * 3 + 0], y = unq[m * 3 + 1], x = unq[m * 3 + 2];
    size_t site = ((size_t)b * GRID0 + y) * GRID0 + x;
    float4 v = *(const float4*)&fv[(size_t)m * 64 + cg * 4];
    st4(img, site * 64 + cg * 4, isb, v);
    if (cg == 0) occ[site] = 1;
}

// ---------------- 3x3 max-dilation, stride 1 ----------------
__global__ __launch_bounds__(256) void dilate1_kernel(const unsigned char* __restrict__ occ,
                                                      unsigned char* __restrict__ occ1)
{
    int idx = blockIdx.x * 256 + threadIdx.x;
    if (idx >= BATCH * GRID0 * GRID0) return;
    int b = idx / (GRID0 * GRID0);
    int r = idx % (GRID0 * GRID0);
    int y = r / GRID0, x = r % GRID0;
    unsigned char v = 0;
#pragma unroll
    for (int dy = -1; dy <= 1; dy++) {
        int yy = y + dy; if (yy < 0 || yy >= GRID0) continue;
#pragma unroll
        for (int dx = -1; dx <= 1; dx++) {
            int xx = x + dx; if (xx < 0 || xx >= GRID0) continue;
            v |= occ[((size_t)b * GRID0 + yy) * GRID0 + xx];
        }
    }
    occ1[idx] = v ? 1 : 0;
}

// ---------------- 3x3 max-dilation, stride 2 ----------------
__global__ __launch_bounds__(256) void dilate2_kernel(const unsigned char* __restrict__ occ1,
                                                      unsigned char* __restrict__ occ2)
{
    int idx = blockIdx.x * 256 + threadIdx.x;
    if (idx >= BATCH * 128 * 128) return;
    int b = idx / (128 * 128);
    int r = idx % (128 * 128);
    int y = r / 128, x = r % 128;
    unsigned char v = 0;
#pragma unroll
    for (int dy = -1; dy <= 1; dy++) {
        int yy = 2 * y + dy; if (yy < 0 || yy >= GRID0) continue;
#pragma unroll
        for (int dx = -1; dx <= 1; dx++) {
            int xx = 2 * x + dx; if (xx < 0 || xx >= GRID0) continue;
            v |= occ1[((size_t)b * GRID0 + yy) * GRID0 + xx];
        }
    }
    occ2[idx] = v ? 1 : 0;
}

// ---------------- direct tiled 3x3 conv (dtype-adaptive I/O, fp32 math) ----------------
template<int CIN, int COUT, int STRIDE, bool ADD_RES>
__global__ __launch_bounds__(256) void conv3x3_kernel(
    void* ob, int in_slot, int out_slot, void* out_ws, int res_slot, int woff,
    const void* __restrict__ gamma, const void* __restrict__ beta,
    const unsigned char* __restrict__ mask, const int* __restrict__ flag,
    int HIN, int WIN, int HOUT, int WOUT)
{
    const int isb = *flag;
    const void* in = actptr(ob, in_slot, isb);
    void* out = out_ws ? out_ws : actptr(ob, out_slot, isb);
    const void* res = ADD_RES ? actptr(ob, res_slot, isb) : nullptr;
    const float* wt = wpool(ob, isb) + woff;

    constexpr int CO_PER = COUT / 16;
    constexpr int X_EXT = 15 * STRIDE + 3;  // 18 (s1) / 33 (s2)
    constexpr int PSTR = CIN + 4;
    __shared__ float s_in[3 * X_EXT * PSTR];

    const int tid = threadIdx.x;
    const int ox0 = blockIdx.x * 16;
    const int oy = blockIdx.y;
    const int b = blockIdx.z;

    constexpr int C4 = CIN / 4;
    const int total4 = 3 * X_EXT * C4;
    for (int i = tid; i < total4; i += 256) {
        int c4 = i % C4;
        int r = i / C4;
        int xo = r % X_EXT;
        int dy = r / X_EXT;
        int yin = oy * STRIDE - 1 + dy;
        int xin = ox0 * STRIDE - 1 + xo;
        float4 v = make_float4(0.f, 0.f, 0.f, 0.f);
        if (yin >= 0 && yin < HIN && xin >= 0 && xin < WIN)
            v = ld4(in, (((size_t)b * HIN + yin) * WIN + xin) * CIN + c4 * 4, isb);
        *(float4*)&s_in[(dy * X_EXT + xo) * PSTR + c4 * 4] = v;
    }
    __syncthreads();

    const int px = tid & 15;
    const int cog = tid >> 4;
    const int co0 = cog * CO_PER;

    float acc[CO_PER];
#pragma unroll
    for (int k = 0; k < CO_PER; k++) acc[k] = 0.f;

#pragma unroll
    for (int dy = 0; dy < 3; dy++) {
#pragma unroll
        for (int dx = 0; dx < 3; dx++) {
            const float* wp = wt + ((size_t)(dy * 3 + dx) * CIN) * COUT + co0;
            const float* sp = s_in + (dy * X_EXT + px * STRIDE + dx) * PSTR;
#pragma unroll 4
            for (int ci = 0; ci < CIN; ci += 4) {
                float4 v = *(const float4*)(sp + ci);
                float va[4] = { v.x, v.y, v.z, v.w };
#pragma unroll
                for (int j = 0; j < 4; j++) {
                    const float* wr = wp + (size_t)(ci + j) * COUT;
                    if constexpr (CO_PER == 4) {
                        float4 w = *(const float4*)wr;
                        acc[0] += va[j] * w.x; acc[1] += va[j] * w.y;
                        acc[2] += va[j] * w.z; acc[3] += va[j] * w.w;
                    } else {
                        float4 w0 = *(const float4*)wr;
                        float4 w1 = *(const float4*)(wr + 4);
                        acc[0] += va[j] * w0.x; acc[1] += va[j] * w0.y;
                        acc[2] += va[j] * w0.z; acc[3] += va[j] * w0.w;
                        acc[4] += va[j] * w1.x; acc[5] += va[j] * w1.y;
                        acc[6] += va[j] * w1.z; acc[7] += va[j] * w1.w;
                    }
                }
            }
        }
    }

    const int ox = ox0 + px;
    const size_t obase = (((size_t)b * HOUT + oy) * WOUT + ox) * COUT + co0;
    const float mk = mask[((size_t)b * HOUT + oy) * WOUT + ox] ? 1.f : 0.f;

    float rv[CO_PER];
    if constexpr (ADD_RES) {
#pragma unroll
        for (int k = 0; k < CO_PER; k += 4) {
            float4 rr = ld4(res, obase + k, isb);
            rv[k] = rr.x; rv[k + 1] = rr.y; rv[k + 2] = rr.z; rv[k + 3] = rr.w;
        }
    }

    float o[CO_PER];
#pragma unroll
    for (int k = 0; k < CO_PER; k++) {
        float z = acc[k] * ldf(gamma, co0 + k, isb) + ldf(beta, co0 + k, isb);
        z *= mk;
        if constexpr (ADD_RES) z += rv[k];
        o[k] = fmaxf(z, 0.f);
    }
#pragma unroll
    for (int k = 0; k < CO_PER; k += 4)
        st4(out, obase + k, isb, make_float4(o[k], o[k + 1], o[k + 2], o[k + 3]));
}

// ---------------- bilinear gather -> out ----------------
__global__ __launch_bounds__(256) void gather_kernel(
    const void* __restrict__ x, const void* __restrict__ feat,
    const int* __restrict__ unq, const int* __restrict__ unq_inv,
    void* __restrict__ out, const int* __restrict__ flag)
{
    const int isb = *flag;
    int idx = blockIdx.x * 256 + threadIdx.x;
    if (idx >= NPTS * 32) return;
    int n = idx >> 5;
    int co = (idx & 31) * 4;
    float fx = ldf(feat, (size_t)n * 16 + 0, isb);
    float fy = ldf(feat, (size_t)n * 16 + 1, isb);
    float px = ((fx - PCMIN) / VOXEL0) / 2.0f;
    float py = ((fy - PCMIN) / VOXEL0) / 2.0f;
    int bi = unq[(size_t)unq_inv[n] * 3 + 0];
    int xf = (int)floorf(px), yf = (int)floorf(py);
    int x0 = min(max(xf, 0), 127), x1 = min(max(xf + 1, 0), 127);
    int y0 = min(max(yf, 0), 127), y1 = min(max(yf + 1, 0), 127);
    float x0f = (float)x0, x1f = (float)x1, y0f = (float)y0, y1f = (float)y1;
    float wa = (x1f - px) * (y1f - py);
    float wb = (x1f - px) * (py - y0f);
    float wc = (px - x0f) * (y1f - py);
    float wd = (px - x0f) * (py - y0f);
    size_t base = (size_t)bi * 128 * 128 * 128;
    float4 Ia = ld4(x, base + ((size_t)y0 * 128 + x0) * 128 + co, isb);
    float4 Ib = ld4(x, base + ((size_t)y1 * 128 + x0) * 128 + co, isb);
    float4 Ic = ld4(x, base + ((size_t)y0 * 128 + x1) * 128 + co, isb);
    float4 Id = ld4(x, base + ((size_t)y1 * 128 + x1) * 128 + co, isb);
    float4 r;
    r.x = Ia.x * wa + Ib.x * wb + Ic.x * wc + Id.x * wd;
    r.y = Ia.y * wa + Ib.y * wb + Ic.y * wc + Id.y * wd;
    r.z = Ia.z * wa + Ib.z * wb + Ic.z * wc + Id.z * wd;
    r.w = Ia.w * wa + Ib.w * wb + Ic.w * wc + Id.w * wd;
    st4(out, (size_t)n * 128 + co, isb, r);
}

extern "C" void kernel_launch(void* const* d_in, const int* in_sizes, int n_in,
                              void* d_out, int out_size, void* d_ws, size_t ws_size,
                              hipStream_t stream)
{
    (void)in_sizes; (void)n_in; (void)out_size; (void)ws_size;
    const int* unq = (const int*)d_in[1];
    const int* unq_inv = (const int*)d_in[2];

    char* ws = (char*)d_ws;
    int* flagp = (int*)(ws + WS_FLAG);
    unsigned char* occ8 = (unsigned char*)(ws + WS_OCC8);
    unsigned char* occ1m = (unsigned char*)(ws + WS_OCC1);
    unsigned char* occ2m = (unsigned char*)(ws + WS_OCC2);
    float* hmax = (float*)(ws + WS_HMAX);
    float* fv = (float*)(ws + WS_FV);
    void* Fx = (void*)(ws + WS_FX);

    probe_kernel<<<1, 64, 0, stream>>>((const unsigned short*)d_in[5], flagp);

    // weights -> fp32 pool at d_out + 3*slot (flag-dependent offset, resolved in-kernel)
    cvt_kernel<<<1, 256, 0, stream>>>(d_in[4], d_out, W0F, 256, flagp);
    cvt_kernel<<<8, 256, 0, stream>>>(d_in[7], d_out, W1F, 2048, flagp);
    cvt_kernel<<<144, 256, 0, stream>>>(d_in[10], d_out, K1D, 36864, flagp);
    cvt_kernel<<<144, 256, 0, stream>>>(d_in[13], d_out, K11, 36864, flagp);
    cvt_kernel<<<144, 256, 0, stream>>>(d_in[16], d_out, K12, 36864, flagp);
    cvt_kernel<<<288, 256, 0, stream>>>(d_in[19], d_out, K2D, 73728, flagp);
    cvt_kernel<<<576, 256, 0, stream>>>(d_in[22], d_out, K21, 147456, flagp);
    cvt_kernel<<<576, 256, 0, stream>>>(d_in[25], d_out, K22, 147456, flagp);

    // img = slot0: zero 32MB covers slot0 in both modes (extra lands in not-yet-written slot1)
    hipMemsetAsync(d_out, 0, SLOT_F, stream);
    hipMemsetAsync(hmax, 0, (size_t)MPIL * 16 * 4, stream);
    hipMemsetAsync(fv, 0, (size_t)MPIL * 64 * 4, stream);
    hipMemsetAsync(occ8, 0, 131072, stream);

    pfn0_kernel<<<(NPTS + 255) / 256, 256, 0, stream>>>(d_in[0], d_out, d_in[5], d_in[6],
                                                        unq_inv, hmax, flagp);
    pfn1_kernel<<<(NPTS + 255) / 256, 256, 0, stream>>>(d_out, hmax, d_in[8], d_in[9],
                                                        unq_inv, fv, flagp);
    scatter_kernel<<<(MPIL * 16) / 256, 256, 0, stream>>>(fv, unq, d_out, occ8, flagp);
    dilate1_kernel<<<(BATCH * GRID0 * GRID0) / 256, 256, 0, stream>>>(occ8, occ1m);
    dilate2_kernel<<<(BATCH * 128 * 128) / 256, 256, 0, stream>>>(occ1m, occ2m);

    dim3 blk(256);
    dim3 g1(16, 256, BATCH), g2(8, 128, BATCH);
    // block 1 (64ch, stride 1): slot0 -> slot1 -> slot2 -> slot0
    conv3x3_kernel<64, 64, 1, false><<<g1, blk, 0, stream>>>(
        d_out, 0, 1, nullptr, 0, K1D, d_in[11], d_in[12], occ1m, flagp, 256, 256, 256, 256);
    conv3x3_kernel<64, 64, 1, false><<<g1, blk, 0, stream>>>(
        d_out, 1, 2, nullptr, 0, K11, d_in[14], d_in[15], occ1m, flagp, 256, 256, 256, 256);
    conv3x3_kernel<64, 64, 1, true><<<g1, blk, 0, stream>>>(
        d_out, 2, 0, nullptr, 1, K12, d_in[17], d_in[18], occ1m, flagp, 256, 256, 256, 256);
    // block 2 (stride 2 then 128ch): slot0 -> slot1 -> slot2 -> Fx (ws)
    conv3x3_kernel<64, 128, 2, false><<<g2, blk, 0, stream>>>(
        d_out, 0, 1, nullptr, 0, K2D, d_in[20], d_in[21], occ2m, flagp, 256, 256, 128, 128);
    conv3x3_kernel<128, 128, 1, false><<<g2, blk, 0, stream>>>(
        d_out, 1, 2, nullptr, 0, K21, d_in[23], d_in[24], occ2m, flagp, 128, 128, 128, 128);
    conv3x3_kernel<128, 128, 1, true><<<g2, blk, 0, stream>>>(
        d_out, 2, 0, Fx, 1, K22, d_in[26], d_in[27], occ2m, flagp, 128, 128, 128, 128);

    // gather reads Fx (ws) + flag (ws), overwrites all of d_out
    gather_kernel<<<(NPTS * 32) / 256, 256, 0, stream>>>(Fx, d_in[0], unq, unq_inv,
                                                         d_out, flagp);
}